// Round 6
// baseline (16.687 us; speedup 1.0000x reference)
//
#include <hip/hip_runtime.h>

#define L_     512
#define GAMMA_ 0.1f

typedef _Float16 h2  __attribute__((ext_vector_type(2)));
typedef _Float16 h8  __attribute__((ext_vector_type(8)));
typedef float    f32x4 __attribute__((ext_vector_type(4)));

struct alignas(16) H8 { h2 h[4]; };

#if __has_builtin(__builtin_amdgcn_fdot2)
#define DOT2(a,b,c) __builtin_amdgcn_fdot2((a),(b),(c),false)
#else
__device__ __forceinline__ float DOT2(h2 a, h2 b, float c) {
    return fmaf((float)a.x,(float)b.x, fmaf((float)a.y,(float)b.y,c));
}
#endif

#if __has_builtin(__builtin_amdgcn_cvt_pkrtz)
#define PK(a,b) __builtin_bit_cast(h2, __builtin_amdgcn_cvt_pkrtz((a),(b)))
#else
__device__ __forceinline__ h2 PK(float a, float b) { return h2{(_Float16)a,(_Float16)b}; }
#endif

// 512 blocks (2/CU -> 2 waves/SIMD for latency overlap), 256 threads.
// Block owns l = blockIdx.x, 8 batch rows. All global loads hoisted to the
// top (sv fragments, W_time, alphas, bias) so cold-HBM latency overlaps.
// W_token staged LINEAR f32 (pure coalesced copy). Scalar embedding (25
// fma/dim/row), f16 xA in XOR-swizzled A-frag layout, RBF = 16 mfma_16x16x32.
__global__ __launch_bounds__(256, 2) void fused_model_kernel(
    const float* __restrict__ x_enc,    // [8,512,7]
    const float* __restrict__ x_mark,   // [8,512,4]
    const float* __restrict__ W_token,  // [512,7,3]
    const float* __restrict__ W_time,   // [512,4]
    const float* __restrict__ sv,       // [50,512]
    const float* __restrict__ alphas,   // [50]
    const float* __restrict__ bias,     // [7]
    float* __restrict__ out)            // [8,512,7]
{
    __shared__ float Wl[512*21];      // 43 KB, linear copy of W_token
    __shared__ h8    xA8[64*16];      // 16 KB, A-frag [kblk][row^swz][8]
    __shared__ float xin[168];        // conv window [b][j][c], j=0..2
    __shared__ float xmk[32];         // marks [b][f]
    __shared__ float xnL[64], xnF[16], part[64];

    const int t = threadIdx.x;
    const int l = blockIdx.x;
    const int w = t >> 6, lane = t & 63, q = lane & 15, g = lane >> 4;
    const int s = w*16 + q, s_eff = (s < 50) ? s : 49;

    // ---- hoisted scalar loads (avoid cold-miss at the tail) ----
    int r_ = 0, c_ = 0; float bias_c = 0.f;
    if (t < 56) { r_ = t / 7; c_ = t - r_*7; bias_c = bias[c_]; }
    const float al_raw = alphas[s_eff];

    // ---- hoisted W_time: thread t needs rows t and t+256 (coalesced f32x4)
    const f32x4* wm4 = (const f32x4*)W_time;
    const f32x4 m0v = wm4[t];
    const f32x4 m1v = wm4[t + 256];

    // ---- sv gather -> f16 B-fragments in registers; snorm from same f16 ----
    const f32x4* svp = (const f32x4*)(sv + s_eff * 512);
    h8 bvs[16];
#pragma unroll
    for (int ks = 0; ks < 16; ++ks) {
        f32x4 a  = svp[(ks*4 + g)*2];
        f32x4 b2 = svp[(ks*4 + g)*2 + 1];
        h2 p0 = PK(a.x, a.y),  p1 = PK(a.z, a.w);
        h2 p2 = PK(b2.x, b2.y), p3 = PK(b2.z, b2.w);
        h8 v;
        v[0]=p0.x; v[1]=p0.y; v[2]=p1.x; v[3]=p1.y;
        v[4]=p2.x; v[5]=p2.y; v[6]=p3.x; v[7]=p3.y;
        bvs[ks] = v;
    }
    float ssq = 0.f;
#pragma unroll
    for (int ks = 0; ks < 16; ++ks) {
        H8 v = __builtin_bit_cast(H8, bvs[ks]);
        ssq = DOT2(v.h[0],v.h[0],ssq); ssq = DOT2(v.h[1],v.h[1],ssq);
        ssq = DOT2(v.h[2],v.h[2],ssq); ssq = DOT2(v.h[3],v.h[3],ssq);
    }
    ssq += __shfl_xor(ssq, 16, 64);
    ssq += __shfl_xor(ssq, 32, 64);    // full ||sv_s||^2 per lane

    // ---- stage conv window + marks ----
    if (t < 168) {
        int b = t/21, rem = t - b*21, j = rem/7, c = rem - j*7;
        int gl = (l - 1 + j) & (L_ - 1);
        xin[t] = x_enc[(b*L_ + gl)*7 + c];
    }
    if (t < 32) {
        int b = t >> 2, f = t & 3;
        xmk[t] = x_mark[(b*L_ + l)*4 + f];
    }

    // ---- stage W_token: pure coalesced float4 copy, linear layout ----
    const f32x4* wt4 = (const f32x4*)W_token;   // 2688 float4
    f32x4* Wl4 = (f32x4*)Wl;
#pragma unroll
    for (int k = 0; k < 10; ++k) Wl4[t + k*256] = wt4[t + k*256];
    if (t < 128) Wl4[t + 2560] = wt4[t + 2560];
    __syncthreads();   // B1

    // ---- embedding: dims {t, t+256}, rows b=0..7 ----
    {
        float w0[21], w1[21];
#pragma unroll
        for (int j = 0; j < 21; ++j) { w0[j] = Wl[t*21 + j]; w1[j] = Wl[(t+256)*21 + j]; }
        const float C1 = -0.017988946039016654f;   // -ln(10000)/512
        float dv0 = __expf(C1 * (float)(t & ~1));
        float dv1 = __expf(C1 * (float)((t + 256) & ~1));
        float ang0 = (float)l * dv0, ang1 = (float)l * dv1;
        float pe0 = (t & 1) ? __cosf(ang0) : __sinf(ang0);
        float pe1 = (t & 1) ? __cosf(ang1) : __sinf(ang1);
        const int k0 = t >> 3, k1 = (t + 256) >> 3;
        const int sw0 = k0 & 7, sw1 = k1 & 7, h = t & 7;
        _Float16* xh = (_Float16*)xA8;
#pragma unroll
        for (int b = 0; b < 8; ++b) {
            float a0 = pe0, a1 = pe1;
#pragma unroll
            for (int c = 0; c < 7; ++c)
#pragma unroll
                for (int kk = 0; kk < 3; ++kk) {
                    float xv = xin[b*21 + kk*7 + c];
                    a0 = fmaf(w0[c*3 + kk], xv, a0);
                    a1 = fmaf(w1[c*3 + kk], xv, a1);
                }
#pragma unroll
            for (int f = 0; f < 4; ++f) {
                float mv = xmk[b*4 + f];
                a0 = fmaf(m0v[f], mv, a0);
                a1 = fmaf(m1v[f], mv, a1);
            }
            xh[k0*128 + (b ^ sw0)*8 + h] = (_Float16)a0;
            xh[k1*128 + (b ^ sw1)*8 + h] = (_Float16)a1;
        }
    }
    __syncthreads();   // B2

    // ---- RBF: 16 mfma over K=512 (rows 8-15 unused garbage, harmless) ----
    f32x4 acc = {0.f, 0.f, 0.f, 0.f};
#pragma unroll
    for (int ks = 0; ks < 16; ++ks) {
        int kblk = ks*4 + g;
        h8 av = xA8[kblk*16 + (q ^ (kblk & 7))];
        acc = __builtin_amdgcn_mfma_f32_16x16x32_f16(av, bvs[ks], acc, 0, 0, 0);
    }

    // ---- xnorm: row q partial over kblks w*16..+15, reduce over g ----
    {
        float xsq = 0.f;
#pragma unroll
        for (int i = 0; i < 4; ++i) {
            int kblk = w*16 + g*4 + i;
            H8 v = __builtin_bit_cast(H8, xA8[kblk*16 + (q ^ (kblk & 7))]);
            xsq = DOT2(v.h[0],v.h[0],xsq); xsq = DOT2(v.h[1],v.h[1],xsq);
            xsq = DOT2(v.h[2],v.h[2],xsq); xsq = DOT2(v.h[3],v.h[3],xsq);
        }
        xsq += __shfl_xor(xsq, 16, 64);
        xsq += __shfl_xor(xsq, 32, 64);
        if (g == 0) xnL[w*16 + q] = xsq;
    }
    __syncthreads();   // B3
    if (t < 16) xnF[t] = xnL[t] + xnL[16+t] + xnL[32+t] + xnL[48+t];
    __syncthreads();   // B4

    // ---- epilogue: dist^2 -> alpha*exp -> sum over this wave's 16 svs ----
    {
        const float alpha = (s < 50) ? al_raw : 0.f;
        float vals[4];
#pragma unroll
        for (int i = 0; i < 4; ++i) {
            int row = g*4 + i;
            float d2 = xnF[row] + ssq - 2.f*acc[i];
            float vv = alpha * __expf(-GAMMA_ * d2);
            vals[i] = vv;
#pragma unroll
            for (int off = 1; off < 16; off <<= 1)
                vals[i] += __shfl_xor(vals[i], off, 64);
        }
        if (q == 0) {
#pragma unroll
            for (int i = 0; i < 4; ++i) part[w*16 + g*4 + i] = vals[i];
        }
    }
    __syncthreads();   // B5

    if (t < 56)
        out[(r_*L_ + l)*7 + c_] =
            part[r_] + part[16 + r_] + part[32 + r_] + part[48 + r_] + bias_c;
}

extern "C" void kernel_launch(void* const* d_in, const int* in_sizes, int n_in,
                              void* d_out, int out_size, void* d_ws, size_t ws_size,
                              hipStream_t stream) {
    (void)d_ws; (void)ws_size; (void)in_sizes; (void)n_in;
    const float* x_enc      = (const float*)d_in[0];
    const float* x_mark_enc = (const float*)d_in[1];
    // d_in[2] (x_dec), d_in[3] (x_mark_dec) unused by the reference.
    const float* W_token    = (const float*)d_in[4];
    const float* W_time     = (const float*)d_in[5];
    const float* sv         = (const float*)d_in[6];
    const float* alphas     = (const float*)d_in[7];
    const float* bias       = (const float*)d_in[8];
    float* out = (float*)d_out;

    fused_model_kernel<<<dim3(L_), dim3(256), 0, stream>>>(
        x_enc, x_mark_enc, W_token, W_time, sv, alphas, bias, out);
}

// Round 7
// 14.990 us; speedup vs baseline: 1.1132x; 1.1132x over previous
//
#include <hip/hip_runtime.h>

#define L_     512
#define GAMMA_ 0.1f

typedef _Float16 h2  __attribute__((ext_vector_type(2)));
typedef _Float16 h8  __attribute__((ext_vector_type(8)));
typedef float    f32x4 __attribute__((ext_vector_type(4)));

struct alignas(16) H8 { h2 h[4]; };

#if __has_builtin(__builtin_amdgcn_fdot2)
#define DOT2(a,b,c) __builtin_amdgcn_fdot2((a),(b),(c),false)
#else
__device__ __forceinline__ float DOT2(h2 a, h2 b, float c) {
    return fmaf((float)a.x,(float)b.x, fmaf((float)a.y,(float)b.y,c));
}
#endif

#if __has_builtin(__builtin_amdgcn_cvt_pkrtz)
#define PK(a,b) __builtin_bit_cast(h2, __builtin_amdgcn_cvt_pkrtz((a),(b)))
#else
__device__ __forceinline__ h2 PK(float a, float b) { return h2{(_Float16)a,(_Float16)b}; }
#endif

// 256 blocks (exactly 1/CU), 256 threads. Block owns 16 rows (8 b x 2 l).
// All global loads issue before the first barrier; sv lives in REGISTERS
// (no LDS round-trip); W_token staged by pure coalesced float4 copy into
// linear LDS (reads are free-2-way since gcd(21,32)=1). Embedding scalar
// (25 fma/dim/row), xA f16 XOR-swizzled A-frags, RBF = 16 mfma_16x16x32_f16.
__global__ __launch_bounds__(256, 1) void fused_model_kernel(
    const float* __restrict__ x_enc,    // [8,512,7]
    const float* __restrict__ x_mark,   // [8,512,4]
    const float* __restrict__ W_token,  // [512,7,3]
    const float* __restrict__ W_time,   // [512,4]
    const float* __restrict__ sv,       // [50,512]
    const float* __restrict__ alphas,   // [50]
    const float* __restrict__ bias,     // [7]
    float* __restrict__ out)            // [8,512,7]
{
    __shared__ float Wl[512*21];      // 43 KB linear W_token
    __shared__ h8    xA8[64*16];      // 16 KB A-frag [kblk][row^swz][8]
    __shared__ float xin[224];        // conv window [b][j=0..3][c]
    __shared__ float xmk[64];         // marks [b][il][f]
    __shared__ float xnL[64], xnF[16], part[64];

    const int t = threadIdx.x;
    const int l0 = blockIdx.x * 2;
    const int w = t >> 6, lane = t & 63, q = lane & 15, g = lane >> 4;
    const int s = w*16 + q, s_eff = (s < 50) ? s : 49;

    // ---- 1. issue sv gathers (consumed only at the MFMA phase) ----
    const f32x4* svp = (const f32x4*)(sv + s_eff * 512);
    f32x4 ga[16], gb[16];
#pragma unroll
    for (int ks = 0; ks < 16; ++ks) {
        ga[ks] = svp[(ks*4 + g)*2];
        gb[ks] = svp[(ks*4 + g)*2 + 1];
    }

    // ---- 2. issue W_time / alphas / bias / xin / marks ----
    const f32x4* wm4 = (const f32x4*)W_time;
    const f32x4 m0v = wm4[t];
    const f32x4 m1v = wm4[t + 256];
    const float al_raw = alphas[s_eff];
    int r_ = 0, c_ = 0; float bias_c = 0.f;
    if (t < 112) { r_ = t / 7; c_ = t - r_*7; bias_c = bias[c_]; }

    if (t < 224) {
        int b = t/28, rem = t - b*28, j = rem/7, c = rem - j*7;
        int gl = (l0 - 1 + j) & (L_ - 1);
        xin[t] = x_enc[(b*L_ + gl)*7 + c];
    }
    if (t < 64) {
        int b = t>>3, il = (t>>2)&1, f = t&3;
        xmk[t] = x_mark[(b*L_ + l0 + il)*4 + f];
    }

    // ---- 3. W_token: coalesced float4 copy, linear layout ----
    const f32x4* wt4 = (const f32x4*)W_token;   // 2688 float4
    f32x4* Wl4 = (f32x4*)Wl;
#pragma unroll
    for (int k = 0; k < 10; ++k) Wl4[t + k*256] = wt4[t + k*256];
    if (t < 128) Wl4[t + 2560] = wt4[t + 2560];

    // ---- 4. sv -> f16 fragments + snorm (fills the load shadow) ----
    h8 bvs[16];
#pragma unroll
    for (int ks = 0; ks < 16; ++ks) {
        f32x4 a = ga[ks], b2 = gb[ks];
        h2 p0 = PK(a.x, a.y),  p1 = PK(a.z, a.w);
        h2 p2 = PK(b2.x, b2.y), p3 = PK(b2.z, b2.w);
        h8 v;
        v[0]=p0.x; v[1]=p0.y; v[2]=p1.x; v[3]=p1.y;
        v[4]=p2.x; v[5]=p2.y; v[6]=p3.x; v[7]=p3.y;
        bvs[ks] = v;
    }
    float ssq = 0.f;
#pragma unroll
    for (int ks = 0; ks < 16; ++ks) {
        H8 v = __builtin_bit_cast(H8, bvs[ks]);
        ssq = DOT2(v.h[0],v.h[0],ssq); ssq = DOT2(v.h[1],v.h[1],ssq);
        ssq = DOT2(v.h[2],v.h[2],ssq); ssq = DOT2(v.h[3],v.h[3],ssq);
    }
    ssq += __shfl_xor(ssq, 16, 64);
    ssq += __shfl_xor(ssq, 32, 64);    // full ||sv_s||^2 per lane
    __syncthreads();   // B1: Wl, xin, xmk ready

    // ---- 5. embedding: dims {t, t+256}, 16 rows ----
    {
        float w0[21], w1[21];
#pragma unroll
        for (int j = 0; j < 21; ++j) { w0[j] = Wl[t*21 + j]; w1[j] = Wl[(t+256)*21 + j]; }
        const float C1 = -0.017988946039016654f;   // -ln(10000)/512
        float dv0 = __expf(C1 * (float)(t & ~1));
        float dv1 = __expf(C1 * (float)((t + 256) & ~1));
        float sn00 = __sinf((float)l0 * dv0),     cs00 = __cosf((float)l0 * dv0);
        float sn01 = __sinf((float)(l0+1) * dv0), cs01 = __cosf((float)(l0+1) * dv0);
        float sn10 = __sinf((float)l0 * dv1),     cs10 = __cosf((float)l0 * dv1);
        float sn11 = __sinf((float)(l0+1) * dv1), cs11 = __cosf((float)(l0+1) * dv1);
        const int odd = t & 1;
        float pe0[2] = { odd ? cs00 : sn00, odd ? cs01 : sn01 };
        float pe1[2] = { odd ? cs10 : sn10, odd ? cs11 : sn11 };
        const int k0 = t >> 3, k1 = (t + 256) >> 3;
        const int sw0 = k0 & 7, sw1 = k1 & 7, h = t & 7;
        _Float16* xh = (_Float16*)xA8;
#pragma unroll
        for (int r = 0; r < 16; ++r) {
            const int b = r & 7, il = r >> 3;
            float a0 = pe0[il], a1 = pe1[il];
            const float* xi = xin + b*28 + il*7;
#pragma unroll
            for (int c = 0; c < 7; ++c)
#pragma unroll
                for (int kk = 0; kk < 3; ++kk) {
                    float xv = xi[kk*7 + c];
                    a0 = fmaf(w0[c*3 + kk], xv, a0);
                    a1 = fmaf(w1[c*3 + kk], xv, a1);
                }
            const float* mk = xmk + (b*2 + il)*4;
#pragma unroll
            for (int f = 0; f < 4; ++f) {
                a0 = fmaf(m0v[f], mk[f], a0);
                a1 = fmaf(m1v[f], mk[f], a1);
            }
            xh[k0*128 + (r ^ sw0)*8 + h] = (_Float16)a0;
            xh[k1*128 + (r ^ sw1)*8 + h] = (_Float16)a1;
        }
    }
    __syncthreads();   // B2: xA ready

    // ---- 6. RBF: 16 mfma over K=512 ----
    f32x4 acc = {0.f, 0.f, 0.f, 0.f};
#pragma unroll
    for (int ks = 0; ks < 16; ++ks) {
        int kblk = ks*4 + g;
        h8 av = xA8[kblk*16 + (q ^ (kblk & 7))];
        acc = __builtin_amdgcn_mfma_f32_16x16x32_f16(av, bvs[ks], acc, 0, 0, 0);
    }

    // ---- 7. xnorm: row q partial over kblks w*16..+15, reduce over g ----
    {
        float xsq = 0.f;
#pragma unroll
        for (int i = 0; i < 4; ++i) {
            int kblk = w*16 + g*4 + i;
            H8 v = __builtin_bit_cast(H8, xA8[kblk*16 + (q ^ (kblk & 7))]);
            xsq = DOT2(v.h[0],v.h[0],xsq); xsq = DOT2(v.h[1],v.h[1],xsq);
            xsq = DOT2(v.h[2],v.h[2],xsq); xsq = DOT2(v.h[3],v.h[3],xsq);
        }
        xsq += __shfl_xor(xsq, 16, 64);
        xsq += __shfl_xor(xsq, 32, 64);
        if (g == 0) xnL[w*16 + q] = xsq;
    }
    __syncthreads();   // B3
    if (t < 16) xnF[t] = xnL[t] + xnL[16+t] + xnL[32+t] + xnL[48+t];
    __syncthreads();   // B4

    // ---- 8. epilogue: dist^2 -> alpha*exp -> sum over this wave's 16 svs ----
    {
        const float alpha = (s < 50) ? al_raw : 0.f;
        float vals[4];
#pragma unroll
        for (int i = 0; i < 4; ++i) {
            int row = g*4 + i;
            float d2 = xnF[row] + ssq - 2.f*acc[i];
            float vv = alpha * __expf(-GAMMA_ * d2);
            vals[i] = vv;
#pragma unroll
            for (int off = 1; off < 16; off <<= 1)
                vals[i] += __shfl_xor(vals[i], off, 64);
        }
        if (q == 0) {
#pragma unroll
            for (int i = 0; i < 4; ++i) part[w*16 + g*4 + i] = vals[i];
        }
    }
    __syncthreads();   // B5

    if (t < 112) {
        const int b = r_ & 7, il = r_ >> 3;
        out[(b*L_ + l0 + il)*7 + c_] =
            part[r_] + part[16 + r_] + part[32 + r_] + part[48 + r_] + bias_c;
    }
}

extern "C" void kernel_launch(void* const* d_in, const int* in_sizes, int n_in,
                              void* d_out, int out_size, void* d_ws, size_t ws_size,
                              hipStream_t stream) {
    (void)d_ws; (void)ws_size; (void)in_sizes; (void)n_in;
    const float* x_enc      = (const float*)d_in[0];
    const float* x_mark_enc = (const float*)d_in[1];
    // d_in[2] (x_dec), d_in[3] (x_mark_dec) unused by the reference.
    const float* W_token    = (const float*)d_in[4];
    const float* W_time     = (const float*)d_in[5];
    const float* sv         = (const float*)d_in[6];
    const float* alphas     = (const float*)d_in[7];
    const float* bias       = (const float*)d_in[8];
    float* out = (float*)d_out;

    fused_model_kernel<<<dim3(L_ / 2), dim3(256), 0, stream>>>(
        x_enc, x_mark_enc, W_token, W_time, sv, alphas, bias, out);
}

// Round 8
// 14.398 us; speedup vs baseline: 1.1590x; 1.0411x over previous
//
#include <hip/hip_runtime.h>

#define L_     512
#define GAMMA_ 0.1f

typedef _Float16 h2  __attribute__((ext_vector_type(2)));
typedef _Float16 h8  __attribute__((ext_vector_type(8)));
typedef float    f32x4 __attribute__((ext_vector_type(4)));

#if __has_builtin(__builtin_amdgcn_cvt_pkrtz)
#define PK(a,b) __builtin_bit_cast(h2, __builtin_amdgcn_cvt_pkrtz((a),(b)))
#else
__device__ __forceinline__ h2 PK(float a, float b) { return h2{(_Float16)a,(_Float16)b}; }
#endif

// 256 blocks (1/CU), 256 threads (4 waves). Block owns 16 rows (8 b x 2 l).
// Critical-path-minimized:
//   1. sv gathered to REGISTERS first; cvt+snorm deferred into the RBF loop
//      so the cold-HBM latency hides under all staging + the embed MFMA.
//   2. Embedding via MFMA: A[16 rows][32 k]=conv window+marks (1 KB LDS),
//      B[32 k][512 d]=W_token/W_time f16 B-frag (32 KB LDS). pe added
//      in-register post-MFMA (fast trig).
//   3. xnorm fused into the embed phase from the f32 accumulators
//      (no post-RBF xnorm phase). 4 barriers total.
__global__ __launch_bounds__(256, 1) void fused_model_kernel(
    const float* __restrict__ x_enc,    // [8,512,7]
    const float* __restrict__ x_mark,   // [8,512,4]
    const float* __restrict__ W_token,  // [512,7,3]
    const float* __restrict__ W_time,   // [512,4]
    const float* __restrict__ sv,       // [50,512]
    const float* __restrict__ alphas,   // [50]
    const float* __restrict__ bias,     // [7]
    float* __restrict__ out)            // [8,512,7]
{
    __shared__ h8 Wb8[32*64];      // 32 KB B-frag: halves (d>>4)*512+(d&15)*32+k
    __shared__ h8 xA8[64*16];      // 16 KB A-frag for RBF: [kblk][row][8]
    __shared__ h8 Axw[16*4];       //  1 KB embed A-frag
    __shared__ float xin[224];     // conv window [b][j=0..3][c]
    __shared__ float xmk[64];      // marks [b][il][f]
    __shared__ float xnp[64];      // xnorm partials [wave][row]
    __shared__ float part[64];     // RBF partial sums [wave][row]

    const int t = threadIdx.x;
    const int l0 = blockIdx.x * 2;
    const int w = t >> 6, lane = t & 63, q = lane & 15, g = lane >> 4;
    const int s = w*16 + q, s_eff = (s < 50) ? s : 49;

    // ---- 1. issue sv gathers (consumed only in the RBF loop, much later) ----
    const f32x4* svp = (const f32x4*)(sv + s_eff * 512);
    f32x4 ga[16], gb[16];
#pragma unroll
    for (int ks = 0; ks < 16; ++ks) {
        ga[ks] = svp[(ks*4 + g)*2];
        gb[ks] = svp[(ks*4 + g)*2 + 1];
    }

    // ---- 2. hoisted scalars ----
    const float al_raw = alphas[s_eff];
    int r_ = 0, c_ = 0; float bias_c = 0.f;
    if (t < 112) { r_ = t / 7; c_ = t - r_*7; bias_c = bias[c_]; }

    // ---- 3. stage W -> f16 B-frag layout ----
    _Float16* Wbh = (_Float16*)Wb8;
    const f32x4* wt4 = (const f32x4*)W_token;      // 2688 float4
#pragma unroll
    for (int kk2 = 0; kk2 < 11; ++kk2) {
        int i4 = t + kk2*256;
        if (i4 < 2688) {
            f32x4 v = wt4[i4];
            int f0 = i4*4;
#pragma unroll
            for (int e = 0; e < 4; ++e) {
                int f = f0 + e;
                int d = f / 21;
                int k = f - d*21;
                float x = (e==0) ? v.x : (e==1) ? v.y : (e==2) ? v.z : v.w;
                Wbh[(d>>4)*512 + (d&15)*32 + k] = (_Float16)x;
            }
        }
    }
    const f32x4* wm4 = (const f32x4*)W_time;       // 512 float4
#pragma unroll
    for (int kk2 = 0; kk2 < 2; ++kk2) {
        int i4 = t + kk2*256;
        f32x4 v = wm4[i4];
        int f0 = i4*4;
#pragma unroll
        for (int e = 0; e < 4; ++e) {
            int f = f0 + e;
            int d = f >> 2;
            int k = 21 + (f & 3);
            float x = (e==0) ? v.x : (e==1) ? v.y : (e==2) ? v.z : v.w;
            Wbh[(d>>4)*512 + (d&15)*32 + k] = (_Float16)x;
        }
    }
#pragma unroll
    for (int dd = 0; dd < 2; ++dd) {               // zero pad k = 25..31
        int d = t + dd*256;
        int base = (d>>4)*512 + (d&15)*32;
#pragma unroll
        for (int k = 25; k < 32; ++k) Wbh[base + k] = (_Float16)0.f;
    }

    // ---- 4. stage conv window + marks ----
    if (t < 224) {
        int b = t/28, rem = t - b*28, j = rem/7, c = rem - j*7;
        int gl = (l0 - 1 + j) & (L_ - 1);
        xin[t] = x_enc[(b*L_ + gl)*7 + c];
    }
    if (t < 64) {
        int b = t>>3, il = (t>>2)&1, f = t&3;
        xmk[t] = x_mark[(b*L_ + l0 + il)*4 + f];
    }
    __syncthreads();   // B1: Wb, xin, xmk ready

    // ---- 5. build embed A fragment: A[row][k] ----
    {
        int r = t >> 4, p = t & 15;
        int il = r >> 3, b = r & 7;
        float v[2];
#pragma unroll
        for (int e = 0; e < 2; ++e) {
            int k = 2*p + e;
            float x;
            if (k < 21) { int c = k/3, kk = k - c*3; x = xin[b*28 + (il+kk)*7 + c]; }
            else if (k < 25) x = xmk[(b*2 + il)*4 + (k - 21)];
            else x = 0.f;
            v[e] = x;
        }
        ((h2*)Axw)[r*16 + p] = h2{(_Float16)v[0], (_Float16)v[1]};
    }
    __syncthreads();   // B2: A ready

    // ---- 6. embed MFMA (wave w -> dtiles w*8..w*8+7) + pe + fused xnorm ----
    {
        h8 av4 = Axw[q*4 + g];
        const float C1 = -0.017988946039016654f;   // -ln(10000)/512
        const int il = g >> 1;                     // rows g*4..g*4+3 share il
        float xsq[4] = {0.f, 0.f, 0.f, 0.f};
#pragma unroll
        for (int tt = 0; tt < 8; ++tt) {
            int dt = w*8 + tt;
            h8 bw = Wb8[dt*64 + q*4 + g];
            f32x4 c4 = {0.f, 0.f, 0.f, 0.f};
            c4 = __builtin_amdgcn_mfma_f32_16x16x32_f16(av4, bw, c4, 0, 0, 0);
            int d = dt*16 + q;
            float dv  = __expf(C1 * (float)(d & ~1));
            float ang = (float)(l0 + il) * dv;
            float pe  = (d & 1) ? __cosf(ang) : __sinf(ang);
#pragma unroll
            for (int i = 0; i < 4; ++i) {
                float e = c4[i] + pe;
                xsq[i] = fmaf(e, e, xsq[i]);
                ((_Float16*)xA8)[(d>>3)*128 + (g*4 + i)*8 + (d&7)] = (_Float16)e;
            }
        }
        // reduce xnorm partials over the 16 q-lanes
#pragma unroll
        for (int i = 0; i < 4; ++i) {
#pragma unroll
            for (int off = 1; off < 16; off <<= 1)
                xsq[i] += __shfl_xor(xsq[i], off, 64);
        }
        if (q == 0) {
#pragma unroll
            for (int i = 0; i < 4; ++i) xnp[w*16 + g*4 + i] = xsq[i];
        }
    }
    __syncthreads();   // B3: xA + xnp ready

    // ---- 7. RBF: cvt sv inline + snorm + 16 mfma over K=512 ----
    float ssq = 0.f;
    f32x4 acc = {0.f, 0.f, 0.f, 0.f};
#pragma unroll
    for (int ks = 0; ks < 16; ++ks) {
        f32x4 a = ga[ks], b2 = gb[ks];
        h2 p0 = PK(a.x, a.y),  p1 = PK(a.z, a.w);
        h2 p2 = PK(b2.x, b2.y), p3 = PK(b2.z, b2.w);
        h8 bv;
        bv[0]=p0.x; bv[1]=p0.y; bv[2]=p1.x; bv[3]=p1.y;
        bv[4]=p2.x; bv[5]=p2.y; bv[6]=p3.x; bv[7]=p3.y;
        ssq = fmaf(a.x,a.x,ssq);   ssq = fmaf(a.y,a.y,ssq);
        ssq = fmaf(a.z,a.z,ssq);   ssq = fmaf(a.w,a.w,ssq);
        ssq = fmaf(b2.x,b2.x,ssq); ssq = fmaf(b2.y,b2.y,ssq);
        ssq = fmaf(b2.z,b2.z,ssq); ssq = fmaf(b2.w,b2.w,ssq);
        int kblk = ks*4 + g;
        h8 av = xA8[kblk*16 + q];
        acc = __builtin_amdgcn_mfma_f32_16x16x32_f16(av, bv, acc, 0, 0, 0);
    }
    ssq += __shfl_xor(ssq, 16, 64);
    ssq += __shfl_xor(ssq, 32, 64);    // full ||sv_s||^2 per lane

    // ---- 8. epilogue: dist^2 -> alpha*exp -> sum over this wave's 16 svs ----
    {
        const float alpha = (s < 50) ? al_raw : 0.f;
        float vals[4];
#pragma unroll
        for (int i = 0; i < 4; ++i) {
            int row = g*4 + i;
            float xn = xnp[row] + xnp[16 + row] + xnp[32 + row] + xnp[48 + row];
            float d2 = xn + ssq - 2.f*acc[i];
            float vv = alpha * __expf(-GAMMA_ * d2);
            vals[i] = vv;
#pragma unroll
            for (int off = 1; off < 16; off <<= 1)
                vals[i] += __shfl_xor(vals[i], off, 64);
        }
        if (q == 0) {
#pragma unroll
            for (int i = 0; i < 4; ++i) part[w*16 + g*4 + i] = vals[i];
        }
    }
    __syncthreads();   // B4

    if (t < 112) {
        const int b = r_ & 7, il = r_ >> 3;
        out[(b*L_ + l0 + il)*7 + c_] =
            part[r_] + part[16 + r_] + part[32 + r_] + part[48 + r_] + bias_c;
    }
}

extern "C" void kernel_launch(void* const* d_in, const int* in_sizes, int n_in,
                              void* d_out, int out_size, void* d_ws, size_t ws_size,
                              hipStream_t stream) {
    (void)d_ws; (void)ws_size; (void)in_sizes; (void)n_in;
    const float* x_enc      = (const float*)d_in[0];
    const float* x_mark_enc = (const float*)d_in[1];
    // d_in[2] (x_dec), d_in[3] (x_mark_dec) unused by the reference.
    const float* W_token    = (const float*)d_in[4];
    const float* W_time     = (const float*)d_in[5];
    const float* sv         = (const float*)d_in[6];
    const float* alphas     = (const float*)d_in[7];
    const float* bias       = (const float*)d_in[8];
    float* out = (float*)d_out;

    fused_model_kernel<<<dim3(L_ / 2), dim3(256), 0, stream>>>(
        x_enc, x_mark_enc, W_token, W_time, sv, alphas, bias, out);
}

// Round 9
// 12.809 us; speedup vs baseline: 1.3027x; 1.1241x over previous
//
#include <hip/hip_runtime.h>

#define L_     512
#define GAMMA_ 0.1f

typedef _Float16 h2  __attribute__((ext_vector_type(2)));
typedef _Float16 h8  __attribute__((ext_vector_type(8)));
typedef float    f32x4 __attribute__((ext_vector_type(4)));

#if __has_builtin(__builtin_amdgcn_cvt_pkrtz)
#define PK(a,b) __builtin_bit_cast(h2, __builtin_amdgcn_cvt_pkrtz((a),(b)))
#else
__device__ __forceinline__ h2 PK(float a, float b) { return h2{(_Float16)a,(_Float16)b}; }
#endif

// 256 blocks (1/CU), 512 threads (8 waves -> 2 waves/SIMD for TLP).
// Same total traffic/reuse as R8, but every per-wave serial chain halves:
//   - sv gathers: 16 f32x4/thread (wave pair splits K)
//   - embed MFMA: 4 dtiles/wave (32 total)
//   - RBF: 8 mfma/wave; wave w and w+4 cover K halves, combined via LDS
// Embedding via MFMA (A=conv+marks frag, B=W f16 frag), pe in-register,
// xnorm fused from f32 accumulators.
__global__ __launch_bounds__(512, 1) void fused_model_kernel(
    const float* __restrict__ x_enc,    // [8,512,7]
    const float* __restrict__ x_mark,   // [8,512,4]
    const float* __restrict__ W_token,  // [512,7,3]
    const float* __restrict__ W_time,   // [512,4]
    const float* __restrict__ sv,       // [50,512]
    const float* __restrict__ alphas,   // [50]
    const float* __restrict__ bias,     // [7]
    float* __restrict__ out)            // [8,512,7]
{
    __shared__ h8 Wb8[32*64];      // 32 KB B-frag halves: (d>>4)*512+(d&15)*32+k
    __shared__ h8 xA8[64*16];      // 16 KB A-frag for RBF: [kblk][row][8]
    __shared__ h8 Axw[16*4];       //  1 KB embed A-frag
    __shared__ float xin[224];     // conv window [b][j=0..3][c]
    __shared__ float xmk[64];      // marks [b][il][f]
    __shared__ float xnp[128];     // xnorm partials [wave][row]
    __shared__ f32x4 accL[4*64];   //  4 KB RBF partial C from waves 4-7
    __shared__ float ssqL[4*64];   //  1 KB snorm partials from waves 4-7
    __shared__ float part[64];     // RBF row sums [wavepair][row]

    const int t  = threadIdx.x;
    const int l0 = blockIdx.x * 2;
    const int w = t >> 6, lane = t & 63, q = lane & 15, g = lane >> 4;
    const int wh = w & 3, kh = w >> 2;          // sv-group, K-half
    const int s = wh*16 + q, s_eff = (s < 50) ? s : 49;

    // ---- 1. issue sv gathers (this wave's K-half only) ----
    const f32x4* svp = (const f32x4*)(sv + s_eff * 512);
    f32x4 ga[8], gb[8];
#pragma unroll
    for (int i = 0; i < 8; ++i) {
        ga[i] = svp[((kh*8 + i)*4 + g)*2];
        gb[i] = svp[((kh*8 + i)*4 + g)*2 + 1];
    }

    // ---- 2. hoisted scalars ----
    const float al_raw = alphas[s_eff];
    int r_ = 0, c_ = 0; float bias_c = 0.f;
    if (t < 112) { r_ = t / 7; c_ = t - r_*7; bias_c = bias[c_]; }

    // ---- 3. stage W -> f16 B-frag layout (512 threads) ----
    _Float16* Wbh = (_Float16*)Wb8;
    const f32x4* wt4 = (const f32x4*)W_token;      // 2688 float4
#pragma unroll
    for (int kk2 = 0; kk2 < 6; ++kk2) {
        int i4 = t + kk2*512;
        if (i4 < 2688) {
            f32x4 v = wt4[i4];
            int f0 = i4*4;
#pragma unroll
            for (int e = 0; e < 4; ++e) {
                int f = f0 + e;
                int d = f / 21;
                int k = f - d*21;
                float x = (e==0) ? v.x : (e==1) ? v.y : (e==2) ? v.z : v.w;
                Wbh[(d>>4)*512 + (d&15)*32 + k] = (_Float16)x;
            }
        }
    }
    {
        const f32x4* wm4 = (const f32x4*)W_time;   // 512 float4
        f32x4 v = wm4[t];
        int f0 = t*4;
#pragma unroll
        for (int e = 0; e < 4; ++e) {
            int f = f0 + e;
            int d = f >> 2;
            int k = 21 + (f & 3);
            float x = (e==0) ? v.x : (e==1) ? v.y : (e==2) ? v.z : v.w;
            Wbh[(d>>4)*512 + (d&15)*32 + k] = (_Float16)x;
        }
    }
    {
        int d = t;                                  // zero pad k = 25..31
        int base = (d>>4)*512 + (d&15)*32;
#pragma unroll
        for (int k = 25; k < 32; ++k) Wbh[base + k] = (_Float16)0.f;
    }

    // ---- 4. stage conv window + marks ----
    if (t < 224) {
        int b = t/28, rem = t - b*28, j = rem/7, c = rem - j*7;
        int gl = (l0 - 1 + j) & (L_ - 1);
        xin[t] = x_enc[(b*L_ + gl)*7 + c];
    }
    if (t < 64) {
        int b = t>>3, il = (t>>2)&1, f = t&3;
        xmk[t] = x_mark[(b*L_ + l0 + il)*4 + f];
    }
    __syncthreads();   // B1: Wb, xin, xmk ready

    // ---- 5. build embed A fragment: A[row][k] (first 256 threads) ----
    if (t < 256) {
        int r = t >> 4, p = t & 15;
        int il = r >> 3, b = r & 7;
        float v[2];
#pragma unroll
        for (int e = 0; e < 2; ++e) {
            int k = 2*p + e;
            float x;
            if (k < 21) { int c = k/3, kk = k - c*3; x = xin[b*28 + (il+kk)*7 + c]; }
            else if (k < 25) x = xmk[(b*2 + il)*4 + (k - 21)];
            else x = 0.f;
            v[e] = x;
        }
        ((h2*)Axw)[r*16 + p] = h2{(_Float16)v[0], (_Float16)v[1]};
    }
    __syncthreads();   // B2: A ready

    // ---- 6. embed MFMA: wave w -> dtiles w*4..w*4+3; pe + fused xnorm ----
    {
        h8 av4 = Axw[q*4 + g];
        const float C1 = -0.017988946039016654f;   // -ln(10000)/512
        const int il = g >> 1;                     // rows g*4..g*4+3 share il
        float xsq[4] = {0.f, 0.f, 0.f, 0.f};
#pragma unroll
        for (int tt = 0; tt < 4; ++tt) {
            int dt = w*4 + tt;
            h8 bw = Wb8[dt*64 + q*4 + g];
            f32x4 c4 = {0.f, 0.f, 0.f, 0.f};
            c4 = __builtin_amdgcn_mfma_f32_16x16x32_f16(av4, bw, c4, 0, 0, 0);
            int d = dt*16 + q;
            float dv  = __expf(C1 * (float)(d & ~1));
            float ang = (float)(l0 + il) * dv;
            float pe  = (d & 1) ? __cosf(ang) : __sinf(ang);
#pragma unroll
            for (int i = 0; i < 4; ++i) {
                float e = c4[i] + pe;
                xsq[i] = fmaf(e, e, xsq[i]);
                ((_Float16*)xA8)[(d>>3)*128 + (g*4 + i)*8 + (d&7)] = (_Float16)e;
            }
        }
#pragma unroll
        for (int i = 0; i < 4; ++i) {
#pragma unroll
            for (int off = 1; off < 16; off <<= 1)
                xsq[i] += __shfl_xor(xsq[i], off, 64);
        }
        if (q == 0) {
#pragma unroll
            for (int i = 0; i < 4; ++i) xnp[w*16 + g*4 + i] = xsq[i];
        }
    }
    __syncthreads();   // B3: xA + xnp ready

    // ---- 7. RBF: this wave's K-half, cvt sv inline + snorm + 8 mfma ----
    float ssq = 0.f;
    f32x4 acc = {0.f, 0.f, 0.f, 0.f};
#pragma unroll
    for (int i = 0; i < 8; ++i) {
        f32x4 a = ga[i], b2 = gb[i];
        h2 p0 = PK(a.x, a.y),  p1 = PK(a.z, a.w);
        h2 p2 = PK(b2.x, b2.y), p3 = PK(b2.z, b2.w);
        h8 bv;
        bv[0]=p0.x; bv[1]=p0.y; bv[2]=p1.x; bv[3]=p1.y;
        bv[4]=p2.x; bv[5]=p2.y; bv[6]=p3.x; bv[7]=p3.y;
        ssq = fmaf(a.x,a.x,ssq);   ssq = fmaf(a.y,a.y,ssq);
        ssq = fmaf(a.z,a.z,ssq);   ssq = fmaf(a.w,a.w,ssq);
        ssq = fmaf(b2.x,b2.x,ssq); ssq = fmaf(b2.y,b2.y,ssq);
        ssq = fmaf(b2.z,b2.z,ssq); ssq = fmaf(b2.w,b2.w,ssq);
        int kblk = (kh*8 + i)*4 + g;
        h8 av = xA8[kblk*16 + q];
        acc = __builtin_amdgcn_mfma_f32_16x16x32_f16(av, bv, acc, 0, 0, 0);
    }
    ssq += __shfl_xor(ssq, 16, 64);
    ssq += __shfl_xor(ssq, 32, 64);    // ||sv||^2 over this K-half

    // ---- 8. combine wave pairs (w, w+4) via LDS ----
    if (kh == 1) {
        accL[wh*64 + lane] = acc;
        ssqL[wh*64 + lane] = ssq;
    }
    __syncthreads();   // B4

    if (kh == 0) {
        f32x4 a2 = accL[wh*64 + lane];
        ssq += ssqL[wh*64 + lane];
#pragma unroll
        for (int i = 0; i < 4; ++i) acc[i] += a2[i];

        const float alpha = (s < 50) ? al_raw : 0.f;
        float vals[4];
#pragma unroll
        for (int i = 0; i < 4; ++i) {
            int row = g*4 + i;
            float xn = 0.f;
#pragma unroll
            for (int j = 0; j < 8; ++j) xn += xnp[j*16 + row];
            float d2 = xn + ssq - 2.f*acc[i];
            float vv = alpha * __expf(-GAMMA_ * d2);
            vals[i] = vv;
#pragma unroll
            for (int off = 1; off < 16; off <<= 1)
                vals[i] += __shfl_xor(vals[i], off, 64);
        }
        if (q == 0) {
#pragma unroll
            for (int i = 0; i < 4; ++i) part[wh*16 + g*4 + i] = vals[i];
        }
    }
    __syncthreads();   // B5

    if (t < 112) {
        const int b = r_ & 7, il = r_ >> 3;
        out[(b*L_ + l0 + il)*7 + c_] =
            part[r_] + part[16 + r_] + part[32 + r_] + part[48 + r_] + bias_c;
    }
}

extern "C" void kernel_launch(void* const* d_in, const int* in_sizes, int n_in,
                              void* d_out, int out_size, void* d_ws, size_t ws_size,
                              hipStream_t stream) {
    (void)d_ws; (void)ws_size; (void)in_sizes; (void)n_in;
    const float* x_enc      = (const float*)d_in[0];
    const float* x_mark_enc = (const float*)d_in[1];
    // d_in[2] (x_dec), d_in[3] (x_mark_dec) unused by the reference.
    const float* W_token    = (const float*)d_in[4];
    const float* W_time     = (const float*)d_in[5];
    const float* sv         = (const float*)d_in[6];
    const float* alphas     = (const float*)d_in[7];
    const float* bias       = (const float*)d_in[8];
    float* out = (float*)d_out;

    fused_model_kernel<<<dim3(L_ / 2), dim3(512), 0, stream>>>(
        x_enc, x_mark_enc, W_token, W_time, sv, alphas, bias, out);
}

// Round 10
// 12.694 us; speedup vs baseline: 1.3145x; 1.0091x over previous
//
#include <hip/hip_runtime.h>

#define L_     512
#define GAMMA_ 0.1f

typedef _Float16 h2  __attribute__((ext_vector_type(2)));
typedef _Float16 h8  __attribute__((ext_vector_type(8)));
typedef float    f32x4 __attribute__((ext_vector_type(4)));

#if __has_builtin(__builtin_amdgcn_cvt_pkrtz)
#define PK(a,b) __builtin_bit_cast(h2, __builtin_amdgcn_cvt_pkrtz((a),(b)))
#else
__device__ __forceinline__ h2 PK(float a, float b) { return h2{(_Float16)a,(_Float16)b}; }
#endif

// 256 blocks (1/CU), 1024 threads (16 waves -> 4 waves/SIMD).
// vs R9: per-wave chains halve again (embed 2 dtiles/wave, RBF 4 mfma/wave,
// K split 4-ways), A-fragment built DIRECTLY by the staging loads (barrier
// B2 and xin/xmk buffers eliminated). 4 barriers total.
__global__ __launch_bounds__(1024, 1) void fused_model_kernel(
    const float* __restrict__ x_enc,    // [8,512,7]
    const float* __restrict__ x_mark,   // [8,512,4]
    const float* __restrict__ W_token,  // [512,7,3]
    const float* __restrict__ W_time,   // [512,4]
    const float* __restrict__ sv,       // [50,512]
    const float* __restrict__ alphas,   // [50]
    const float* __restrict__ bias,     // [7]
    float* __restrict__ out)            // [8,512,7]
{
    __shared__ h8 Wb8[32*64];      // 32 KB B-frag halves: (d>>4)*512+(d&15)*32+k
    __shared__ h8 xA8[64*16];      // 16 KB A-frag for RBF: [kblk][row][8]
    __shared__ h8 Axw[16*4];       //  1 KB embed A-frag (halves: row*32+k)
    __shared__ float xnp[16*16];   //  1 KB xnorm partials [wave][row]
    __shared__ f32x4 accL[3*4*64]; // 12 KB RBF partial C from K-quarters 1..3
    __shared__ float ssqL[3*4*64]; //  3 KB snorm partials from quarters 1..3
    __shared__ float part[64];     // RBF row sums [svgroup][row]

    const int t  = threadIdx.x;
    const int l0 = blockIdx.x * 2;
    const int w = t >> 6, lane = t & 63, q = lane & 15, g = lane >> 4;
    const int wh = w & 3, kq = w >> 2;          // sv-group, K-quarter
    const int s = wh*16 + q, s_eff = (s < 50) ? s : 49;

    // ---- 1. issue sv gathers (this wave's K-quarter; consumed at RBF) ----
    const f32x4* svp = (const f32x4*)(sv + s_eff * 512);
    f32x4 ga[4], gb[4];
#pragma unroll
    for (int i = 0; i < 4; ++i) {
        int kblk = (kq*4 + i)*4 + g;
        ga[i] = svp[kblk*2];
        gb[i] = svp[kblk*2 + 1];
    }

    // ---- 2. hoisted scalars ----
    const float al_raw = alphas[s_eff];
    int r_ = 0, c_ = 0; float bias_c = 0.f;
    if (t < 112) { r_ = t / 7; c_ = t - r_*7; bias_c = bias[c_]; }

    // ---- 3. stage W -> f16 B-frag layout (1024 threads, 3 iters) ----
    _Float16* Wbh = (_Float16*)Wb8;
    const f32x4* wt4 = (const f32x4*)W_token;      // 2688 float4
#pragma unroll
    for (int kk2 = 0; kk2 < 3; ++kk2) {
        int i4 = t + kk2*1024;
        if (i4 < 2688) {
            f32x4 v = wt4[i4];
            int f0 = i4*4;
#pragma unroll
            for (int e = 0; e < 4; ++e) {
                int f = f0 + e;
                int d = f / 21;
                int k = f - d*21;
                float x = (e==0) ? v.x : (e==1) ? v.y : (e==2) ? v.z : v.w;
                Wbh[(d>>4)*512 + (d&15)*32 + k] = (_Float16)x;
            }
        }
    }
    if (t < 512) {
        const f32x4* wm4 = (const f32x4*)W_time;   // 512 float4
        f32x4 v = wm4[t];
        int f0 = t*4;
#pragma unroll
        for (int e = 0; e < 4; ++e) {
            int f = f0 + e;
            int d = f >> 2;
            int k = 21 + (f & 3);
            float x = (e==0) ? v.x : (e==1) ? v.y : (e==2) ? v.z : v.w;
            Wbh[(d>>4)*512 + (d&15)*32 + k] = (_Float16)x;
        }
        int d = t;                                  // zero pad k = 25..31
        int base = (d>>4)*512 + (d&15)*32;
#pragma unroll
        for (int k = 25; k < 32; ++k) Wbh[base + k] = (_Float16)0.f;
    }

    // ---- 4. stage conv window + marks DIRECTLY into embed A-frag ----
    {
        _Float16* Ah = (_Float16*)Axw;             // half index = row*32 + k
        if (t < 224) {                             // x_enc window loads
            int b = t/28, rem = t - b*28, j = rem/7, c = rem - j*7;
            int gl = (l0 - 1 + j) & (L_ - 1);
            float x = x_enc[(b*L_ + gl)*7 + c];
            _Float16 hx = (_Float16)x;
#pragma unroll
            for (int il = 0; il < 2; ++il) {
                int kk = j - il;
                if (kk >= 0 && kk <= 2)
                    Ah[(il*8 + b)*32 + c*3 + kk] = hx;
            }
        }
        if (t < 64) {                              // marks
            int b = t>>3, il = (t>>2)&1, f = t&3;
            float m = x_mark[(b*L_ + l0 + il)*4 + f];
            Ah[(il*8 + b)*32 + 21 + f] = (_Float16)m;
        }
        if (t < 112) {                             // zero pad k = 25..31
            int r = t / 7, k = 25 + (t - (t/7)*7);
            Ah[r*32 + k] = (_Float16)0.f;
        }
    }
    __syncthreads();   // B1: Wb + A-frag ready

    // ---- 5. embed MFMA: wave w -> dtiles w*2, w*2+1; pe + fused xnorm ----
    {
        h8 av4 = Axw[q*4 + g];
        const float C1 = -0.017988946039016654f;   // -ln(10000)/512
        const int il = g >> 1;                     // rows g*4..g*4+3 share il
        float xsq[4] = {0.f, 0.f, 0.f, 0.f};
#pragma unroll
        for (int tt = 0; tt < 2; ++tt) {
            int dt = w*2 + tt;
            h8 bw = Wb8[dt*64 + q*4 + g];
            f32x4 c4 = {0.f, 0.f, 0.f, 0.f};
            c4 = __builtin_amdgcn_mfma_f32_16x16x32_f16(av4, bw, c4, 0, 0, 0);
            int d = dt*16 + q;
            float dv  = __expf(C1 * (float)(d & ~1));
            float ang = (float)(l0 + il) * dv;
            float pe  = (d & 1) ? __cosf(ang) : __sinf(ang);
#pragma unroll
            for (int i = 0; i < 4; ++i) {
                float e = c4[i] + pe;
                xsq[i] = fmaf(e, e, xsq[i]);
                ((_Float16*)xA8)[(d>>3)*128 + (g*4 + i)*8 + (d&7)] = (_Float16)e;
            }
        }
#pragma unroll
        for (int i = 0; i < 4; ++i) {
#pragma unroll
            for (int off = 1; off < 16; off <<= 1)
                xsq[i] += __shfl_xor(xsq[i], off, 64);
        }
        if (q == 0) {
#pragma unroll
            for (int i = 0; i < 4; ++i) xnp[w*16 + g*4 + i] = xsq[i];
        }
    }
    __syncthreads();   // B2: xA + xnp ready

    // ---- 6. RBF: this wave's K-quarter, cvt sv inline + snorm + 4 mfma ----
    float ssq = 0.f;
    f32x4 acc = {0.f, 0.f, 0.f, 0.f};
#pragma unroll
    for (int i = 0; i < 4; ++i) {
        f32x4 a = ga[i], b2 = gb[i];
        h2 p0 = PK(a.x, a.y),  p1 = PK(a.z, a.w);
        h2 p2 = PK(b2.x, b2.y), p3 = PK(b2.z, b2.w);
        h8 bv;
        bv[0]=p0.x; bv[1]=p0.y; bv[2]=p1.x; bv[3]=p1.y;
        bv[4]=p2.x; bv[5]=p2.y; bv[6]=p3.x; bv[7]=p3.y;
        ssq = fmaf(a.x,a.x,ssq);   ssq = fmaf(a.y,a.y,ssq);
        ssq = fmaf(a.z,a.z,ssq);   ssq = fmaf(a.w,a.w,ssq);
        ssq = fmaf(b2.x,b2.x,ssq); ssq = fmaf(b2.y,b2.y,ssq);
        ssq = fmaf(b2.z,b2.z,ssq); ssq = fmaf(b2.w,b2.w,ssq);
        int kblk = (kq*4 + i)*4 + g;
        h8 av = xA8[kblk*16 + q];
        acc = __builtin_amdgcn_mfma_f32_16x16x32_f16(av, bv, acc, 0, 0, 0);
    }
    ssq += __shfl_xor(ssq, 16, 64);
    ssq += __shfl_xor(ssq, 32, 64);    // ||sv||^2 over this K-quarter

    // ---- 7. combine K-quarters via LDS ----
    if (kq != 0) {
        accL[((kq-1)*4 + wh)*64 + lane] = acc;
        ssqL[((kq-1)*4 + wh)*64 + lane] = ssq;
    }
    __syncthreads();   // B3

    if (kq == 0) {
#pragma unroll
        for (int j = 0; j < 3; ++j) {
            f32x4 a2 = accL[(j*4 + wh)*64 + lane];
            ssq += ssqL[(j*4 + wh)*64 + lane];
#pragma unroll
            for (int i = 0; i < 4; ++i) acc[i] += a2[i];
        }
        const float alpha = (s < 50) ? al_raw : 0.f;
        float vals[4];
#pragma unroll
        for (int i = 0; i < 4; ++i) {
            int row = g*4 + i;
            float xn = 0.f;
#pragma unroll
            for (int j = 0; j < 16; ++j) xn += xnp[j*16 + row];
            float d2 = xn + ssq - 2.f*acc[i];
            float vv = alpha * __expf(-GAMMA_ * d2);
            vals[i] = vv;
#pragma unroll
            for (int off = 1; off < 16; off <<= 1)
                vals[i] += __shfl_xor(vals[i], off, 64);
        }
        if (q == 0) {
#pragma unroll
            for (int i = 0; i < 4; ++i) part[wh*16 + g*4 + i] = vals[i];
        }
    }
    __syncthreads();   // B4

    if (t < 112) {
        const int b = r_ & 7, il = r_ >> 3;
        out[(b*L_ + l0 + il)*7 + c_] =
            part[r_] + part[16 + r_] + part[32 + r_] + part[48 + r_] + bias_c;
    }
}

extern "C" void kernel_launch(void* const* d_in, const int* in_sizes, int n_in,
                              void* d_out, int out_size, void* d_ws, size_t ws_size,
                              hipStream_t stream) {
    (void)d_ws; (void)ws_size; (void)in_sizes; (void)n_in;
    const float* x_enc      = (const float*)d_in[0];
    const float* x_mark_enc = (const float*)d_in[1];
    // d_in[2] (x_dec), d_in[3] (x_mark_dec) unused by the reference.
    const float* W_token    = (const float*)d_in[4];
    const float* W_time     = (const float*)d_in[5];
    const float* sv         = (const float*)d_in[6];
    const float* alphas     = (const float*)d_in[7];
    const float* bias       = (const float*)d_in[8];
    float* out = (float*)d_out;

    fused_model_kernel<<<dim3(L_ / 2), dim3(1024), 0, stream>>>(
        x_enc, x_mark_enc, W_token, W_time, sv, alphas, bias, out);
}